// Round 1
// baseline (168.480 us; speedup 1.0000x reference)
//
#include <hip/hip_runtime.h>

// ---------- types ----------
typedef __bf16 bf16x8 __attribute__((ext_vector_type(8)));
typedef float  f32x4  __attribute__((ext_vector_type(4)));

__device__ __forceinline__ unsigned short f2bf(float f) {
  unsigned int u = __float_as_uint(f);
  u = u + 0x7fffu + ((u >> 16) & 1u);   // RNE
  return (unsigned short)(u >> 16);
}

// global_load_lds, 16B per lane; LDS dest = wave-uniform base + lane*16
#define GLD16(src, dst)                                                        \
  __builtin_amdgcn_global_load_lds(                                            \
      (const __attribute__((address_space(1))) void*)(src),                    \
      (__attribute__((address_space(3))) void*)(dst), 16, 0, 0)

// All LDS tiles here have 128-byte rows; swizzle: byte ^= (row&7)<<4.

// ---------- 1. cast x -> bf16 ----------
__global__ __launch_bounds__(256) void k_cast_x(const float* __restrict__ x,
                                                unsigned short* __restrict__ xb,
                                                int n4) {
  int stride = gridDim.x * blockDim.x;
  for (int i = blockIdx.x * blockDim.x + threadIdx.x; i < n4; i += stride) {
    float4 v = reinterpret_cast<const float4*>(x)[i];
    ushort4 o;
    o.x = f2bf(v.x); o.y = f2bf(v.y); o.z = f2bf(v.z); o.w = f2bf(v.w);
    reinterpret_cast<ushort4*>(xb)[i] = o;
  }
}

// ---------- 2. W_qkv [2048][192] -> bf16 W^T [192][2048] ----------
__global__ __launch_bounds__(256) void k_tr_wq(const float* __restrict__ W,
                                               unsigned short* __restrict__ WT) {
  int idx = blockIdx.x * 256 + threadIdx.x;   // 192*2048
  int c = idx >> 11, k = idx & 2047;
  WT[idx] = f2bf(W[k * 192 + c]);
}

// ---------- 3. W_proj [64][2048] -> bf16 W^T [2048][64] ----------
__global__ __launch_bounds__(256) void k_tr_wp(const float* __restrict__ W,
                                               unsigned short* __restrict__ WT) {
  int idx = blockIdx.x * 256 + threadIdx.x;   // 2048*64
  int n = idx >> 6, d = idx & 63;
  WT[idx] = f2bf(W[d * 2048 + n]);
}

// ---------- 4. QKV GEMM: [16384,2048] x [2048,64(per j)] ----------
// grid (128, 3): j = 0:q 1:k 2:v.  BM=128, BN=64, BK=64, 4 waves (2x2).
__global__ __launch_bounds__(256) void k_qkv(const unsigned short* __restrict__ xb,
                                             const unsigned short* __restrict__ wqT,
                                             const float* __restrict__ b_qkv,
                                             unsigned short* __restrict__ qb,
                                             unsigned short* __restrict__ kb,
                                             unsigned short* __restrict__ vt) {
  __shared__ unsigned short sA[128 * 64];   // [row][k] bf16, 128B rows, swizzled
  __shared__ unsigned short sB[64 * 64];    // [n][k]
  const int t = threadIdx.x;
  const int lane = t & 63, w = t >> 6;
  const int l15 = lane & 15, l4 = lane >> 4;
  const int wm = w >> 1, wn = w & 1;
  const int m0 = blockIdx.x * 128;
  const int j  = blockIdx.y;
  f32x4 acc[4][2] = {};
  const char* aBase = (const char*)xb;
  const char* bBase = (const char*)wqT;
  for (int kt = 0; kt < 32; ++kt) {
#pragma unroll
    for (int p = 0; p < 4; ++p) {           // A tile: 16KB
      int L = p * 4096 + t * 16;
      int row = L >> 7;
      int cb = (L & 127) ^ ((row & 7) << 4);
      GLD16(aBase + (size_t)(m0 + row) * 4096 + kt * 128 + cb,
            (char*)sA + p * 4096 + (w << 10));
    }
#pragma unroll
    for (int p = 0; p < 2; ++p) {           // B tile: 8KB
      int L = p * 4096 + t * 16;
      int row = L >> 7;
      int cb = (L & 127) ^ ((row & 7) << 4);
      GLD16(bBase + (size_t)(j * 64 + row) * 4096 + kt * 128 + cb,
            (char*)sB + p * 4096 + (w << 10));
    }
    __syncthreads();
#pragma unroll
    for (int kk = 0; kk < 2; ++kk) {
      int cb = kk * 64 + l4 * 16;
      bf16x8 af[4], bfr[2];
#pragma unroll
      for (int m = 0; m < 4; ++m) {
        int r = wm * 64 + m * 16 + l15;
        af[m] = *(const bf16x8*)((const char*)sA + r * 128 + (cb ^ ((r & 7) << 4)));
      }
#pragma unroll
      for (int n = 0; n < 2; ++n) {
        int r = wn * 32 + n * 16 + l15;
        bfr[n] = *(const bf16x8*)((const char*)sB + r * 128 + (cb ^ ((r & 7) << 4)));
      }
#pragma unroll
      for (int m = 0; m < 4; ++m)
#pragma unroll
        for (int n = 0; n < 2; ++n)
          acc[m][n] = __builtin_amdgcn_mfma_f32_16x16x32_bf16(af[m], bfr[n], acc[m][n], 0, 0, 0);
    }
    __syncthreads();
  }
  // epilogue: C/D layout col=lane&15, row=(lane>>4)*4+reg
#pragma unroll
  for (int m = 0; m < 4; ++m)
#pragma unroll
    for (int n = 0; n < 2; ++n)
#pragma unroll
      for (int r = 0; r < 4; ++r) {
        int c = wn * 32 + n * 16 + l15;
        int grow = m0 + wm * 64 + m * 16 + l4 * 4 + r;
        float v = acc[m][n][r] + b_qkv[j * 64 + c];
        unsigned short h = f2bf(v);
        if (j == 0)      qb[(size_t)grow * 64 + c] = h;
        else if (j == 1) kb[(size_t)grow * 64 + c] = h;
        else {           // v stored transposed: [b][64][2048]
          int bb = grow >> 11, nn = grow & 2047;
          vt[((size_t)bb * 64 + c) * 2048 + nn] = h;
        }
      }
}

// ---------- 5. flash attention ----------
// grid (32, 8) = (q-tile of 64, batch). 4 waves, wave w owns q-rows q0+w*16..+15.
__global__ __launch_bounds__(256) void k_attn(const unsigned short* __restrict__ qb,
                                              const unsigned short* __restrict__ kb,
                                              const unsigned short* __restrict__ vt,
                                              unsigned short* __restrict__ ctxb) {
  __shared__ unsigned short sK[64 * 64];       // [kv][dim]
  __shared__ unsigned short sV[64 * 64];       // [dim][kv]  (V^T)
  __shared__ unsigned short sP[4 * 16 * 64];   // per-wave [16 qrow][64 kv]
  const int t = threadIdx.x;
  const int lane = t & 63, w = t >> 6;
  const int l15 = lane & 15, l4 = lane >> 4;
  const int bb = blockIdx.y;
  const int q0 = blockIdx.x * 64 + w * 16;
  const unsigned short* qrow = qb + ((size_t)bb * 2048 + q0 + l15) * 64;
  bf16x8 aq[2];
  aq[0] = *(const bf16x8*)(qrow + l4 * 8);       // A-frag: row=l&15, k=(l>>4)*8+j
  aq[1] = *(const bf16x8*)(qrow + 32 + l4 * 8);
  f32x4 ctx[4] = {};
  float mrow[4] = {-1e30f, -1e30f, -1e30f, -1e30f};
  float lrow[4] = {0.f, 0.f, 0.f, 0.f};
  const char* kBase = (const char*)kb + (size_t)bb * 2048 * 128;
  const char* vBase = (const char*)vt + (size_t)bb * 64 * 4096;
  char* pw = (char*)sP + (w << 11);
  for (int kt = 0; kt < 32; ++kt) {
#pragma unroll
    for (int p = 0; p < 2; ++p) {
      int L = p * 4096 + t * 16;
      int row = L >> 7;
      int cb = (L & 127) ^ ((row & 7) << 4);
      GLD16(kBase + (size_t)(kt * 64 + row) * 128 + cb, (char*)sK + p * 4096 + (w << 10));
      GLD16(vBase + (size_t)row * 4096 + kt * 128 + cb, (char*)sV + p * 4096 + (w << 10));
    }
    __syncthreads();
    // S = Q K^T  (s[nf]: rows (l>>4)*4+r, col kv = nf*16 + (l&15))
    f32x4 s[4] = {};
#pragma unroll
    for (int kk = 0; kk < 2; ++kk) {
      int cb = kk * 64 + l4 * 16;
#pragma unroll
      for (int nf = 0; nf < 4; ++nf) {
        int r = nf * 16 + l15;
        bf16x8 bk = *(const bf16x8*)((const char*)sK + r * 128 + (cb ^ ((r & 7) << 4)));
        s[nf] = __builtin_amdgcn_mfma_f32_16x16x32_bf16(aq[kk], bk, s[nf], 0, 0, 0);
      }
    }
    // online softmax; row r of this lane's 4 rows lives in 16 lanes (same l>>4)
#pragma unroll
    for (int r = 0; r < 4; ++r) {
      float cm = fmaxf(fmaxf(s[0][r], s[1][r]), fmaxf(s[2][r], s[3][r])) * 0.125f;
      cm = fmaxf(cm, __shfl_xor(cm, 1));
      cm = fmaxf(cm, __shfl_xor(cm, 2));
      cm = fmaxf(cm, __shfl_xor(cm, 4));
      cm = fmaxf(cm, __shfl_xor(cm, 8));
      float mn = fmaxf(mrow[r], cm);
      float alpha = __expf(mrow[r] - mn);
      mrow[r] = mn;
      float rs = 0.f;
#pragma unroll
      for (int nf = 0; nf < 4; ++nf) {
        float p = __expf(s[nf][r] * 0.125f - mn);
        s[nf][r] = p;
        rs += p;
      }
      rs += __shfl_xor(rs, 1); rs += __shfl_xor(rs, 2);
      rs += __shfl_xor(rs, 4); rs += __shfl_xor(rs, 8);
      lrow[r] = lrow[r] * alpha + rs;
#pragma unroll
      for (int nf = 0; nf < 4; ++nf) ctx[nf][r] *= alpha;
    }
    // P (D-layout) -> per-wave LDS (A-layout source), bf16, swizzled
#pragma unroll
    for (int nf = 0; nf < 4; ++nf)
#pragma unroll
      for (int r = 0; r < 4; ++r) {
        int row = l4 * 4 + r;
        int cbb = (nf * 16 + l15) * 2;
        *(unsigned short*)(pw + row * 128 + (cbb ^ ((row & 7) << 4))) = f2bf(s[nf][r]);
      }
    // ctx += P V
#pragma unroll
    for (int kk = 0; kk < 2; ++kk) {
      int cb = kk * 64 + l4 * 16;
      int rp = l15;
      bf16x8 pa = *(const bf16x8*)(pw + rp * 128 + (cb ^ ((rp & 7) << 4)));
#pragma unroll
      for (int nf = 0; nf < 4; ++nf) {
        int rv = nf * 16 + l15;
        bf16x8 bv = *(const bf16x8*)((const char*)sV + rv * 128 + (cb ^ ((rv & 7) << 4)));
        ctx[nf] = __builtin_amdgcn_mfma_f32_16x16x32_bf16(pa, bv, ctx[nf], 0, 0, 0);
      }
    }
    __syncthreads();
  }
#pragma unroll
  for (int nf = 0; nf < 4; ++nf)
#pragma unroll
    for (int r = 0; r < 4; ++r) {
      int qr = q0 + l4 * 4 + r;
      int d = nf * 16 + l15;
      ctxb[((size_t)bb * 2048 + qr) * 64 + d] = f2bf(ctx[nf][r] / lrow[r]);
    }
}

// ---------- 6. proj GEMM: [16384,64] x [64,2048] + bias -> fp32 ----------
// grid (256, 8). BM=64, BN=256 (wave owns 64 cols), K=64 in one shot.
__global__ __launch_bounds__(256) void k_proj(const unsigned short* __restrict__ ctxb,
                                              const unsigned short* __restrict__ wpT,
                                              const float* __restrict__ b_proj,
                                              float* __restrict__ out) {
  __shared__ unsigned short sA[64 * 64];     // [row][k]
  __shared__ unsigned short sB[256 * 64];    // [n][k]
  const int t = threadIdx.x;
  const int lane = t & 63, w = t >> 6;
  const int l15 = lane & 15, l4 = lane >> 4;
  const int m0 = blockIdx.x * 64;
  const int n0 = blockIdx.y * 256;
#pragma unroll
  for (int p = 0; p < 2; ++p) {
    int L = p * 4096 + t * 16;
    int row = L >> 7;
    int cb = (L & 127) ^ ((row & 7) << 4);
    GLD16((const char*)ctxb + (size_t)(m0 + row) * 128 + cb,
          (char*)sA + p * 4096 + (w << 10));
  }
#pragma unroll
  for (int p = 0; p < 8; ++p) {
    int L = p * 4096 + t * 16;
    int row = L >> 7;
    int cb = (L & 127) ^ ((row & 7) << 4);
    GLD16((const char*)wpT + (size_t)(n0 + row) * 128 + cb,
          (char*)sB + p * 4096 + (w << 10));
  }
  __syncthreads();
  f32x4 acc[4][4] = {};
#pragma unroll
  for (int kk = 0; kk < 2; ++kk) {
    int cb = kk * 64 + l4 * 16;
    bf16x8 af[4], bfr[4];
#pragma unroll
    for (int m = 0; m < 4; ++m) {
      int r = m * 16 + l15;
      af[m] = *(const bf16x8*)((const char*)sA + r * 128 + (cb ^ ((r & 7) << 4)));
    }
#pragma unroll
    for (int n = 0; n < 4; ++n) {
      int r = w * 64 + n * 16 + l15;
      bfr[n] = *(const bf16x8*)((const char*)sB + r * 128 + (cb ^ ((r & 7) << 4)));
    }
#pragma unroll
    for (int m = 0; m < 4; ++m)
#pragma unroll
      for (int n = 0; n < 4; ++n)
        acc[m][n] = __builtin_amdgcn_mfma_f32_16x16x32_bf16(af[m], bfr[n], acc[m][n], 0, 0, 0);
  }
#pragma unroll
  for (int m = 0; m < 4; ++m)
#pragma unroll
    for (int n = 0; n < 4; ++n)
#pragma unroll
      for (int r = 0; r < 4; ++r) {
        int grow = m0 + m * 16 + l4 * 4 + r;
        int gcol = n0 + w * 64 + n * 16 + l15;
        out[(size_t)grow * 2048 + gcol] = acc[m][n][r] + b_proj[gcol];
      }
}

// ---------- launch ----------
extern "C" void kernel_launch(void* const* d_in, const int* in_sizes, int n_in,
                              void* d_out, int out_size, void* d_ws, size_t ws_size,
                              hipStream_t stream) {
  const float* x      = (const float*)d_in[0];
  const float* W_qkv  = (const float*)d_in[1];
  const float* b_qkv  = (const float*)d_in[2];
  const float* W_proj = (const float*)d_in[3];
  const float* b_proj = (const float*)d_in[4];
  float* out = (float*)d_out;

  unsigned short* ws  = (unsigned short*)d_ws;
  unsigned short* xbf = ws;                                    // 16384*2048
  unsigned short* wqT = xbf + (size_t)16384 * 2048;            // 192*2048
  unsigned short* wpT = wqT + (size_t)192 * 2048;              // 2048*64
  unsigned short* qb  = wpT + (size_t)2048 * 64;               // 16384*64
  unsigned short* kb  = qb  + (size_t)16384 * 64;
  unsigned short* vt  = kb  + (size_t)16384 * 64;              // [8][64][2048]
  unsigned short* ctxb= vt  + (size_t)16384 * 64;              // 16384*64

  k_cast_x<<<2048, 256, 0, stream>>>(x, xbf, 16384 * 2048 / 4);
  k_tr_wq<<<(192 * 2048) / 256, 256, 0, stream>>>(W_qkv, wqT);
  k_tr_wp<<<(2048 * 64) / 256, 256, 0, stream>>>(W_proj, wpT);
  k_qkv<<<dim3(128, 3), 256, 0, stream>>>(xbf, wqT, b_qkv, qb, kb, vt);
  k_attn<<<dim3(32, 8), 256, 0, stream>>>(qb, kb, vt, ctxb);
  k_proj<<<dim3(256, 8), 256, 0, stream>>>(ctxb, wpT, b_proj, out);
}

// Round 2
// 119.151 us; speedup vs baseline: 1.4140x; 1.4140x over previous
//
#include <hip/hip_runtime.h>

// ---------- types ----------
typedef __bf16 bf16x8 __attribute__((ext_vector_type(8)));
typedef unsigned short u16x8 __attribute__((ext_vector_type(8)));
typedef float  f32x4  __attribute__((ext_vector_type(4)));

__device__ __forceinline__ unsigned short f2bf(float f) {
  unsigned int u = __float_as_uint(f);
  u = u + 0x7fffu + ((u >> 16) & 1u);   // RNE
  return (unsigned short)(u >> 16);
}

// global_load_lds, 16B per lane; LDS dest = wave-uniform base + lane*16
#define GLD16(src, dst)                                                        \
  __builtin_amdgcn_global_load_lds(                                            \
      (const __attribute__((address_space(1))) void*)(src),                    \
      (__attribute__((address_space(3))) void*)(dst), 16, 0, 0)

// All LDS tiles have 128-byte rows; swizzle: byte ^= (row&7)<<4 (both sides).

// ---------- 1. W_qkv [2048][192] -> bf16 W^T [192][2048] ----------
__global__ __launch_bounds__(256) void k_tr_wq(const float* __restrict__ W,
                                               unsigned short* __restrict__ WT) {
  int idx = blockIdx.x * 256 + threadIdx.x;   // 192*2048
  int c = idx >> 11, k = idx & 2047;
  WT[idx] = f2bf(W[k * 192 + c]);
}

// ---------- 2. W_proj [64][2048] -> bf16 W^T [2048][64] ----------
__global__ __launch_bounds__(256) void k_tr_wp(const float* __restrict__ W,
                                               unsigned short* __restrict__ WT) {
  int idx = blockIdx.x * 256 + threadIdx.x;   // 2048*64
  int n = idx >> 6, d = idx & 63;
  WT[idx] = f2bf(W[d * 2048 + n]);
}

// ---------- 3. fused QKV GEMM: [16384,2048] x [2048,192] ----------
// BM=64, BN=192 (q|k|v), BK=64. 512 threads = 8 waves (2M x 4N), grid 256.
// A staged from fp32 x with in-flight cast (T14 split); B via global_load_lds.
// Double-buffered LDS, one barrier per K-step (T3 minimum).
__global__ __launch_bounds__(512) void k_qkv(const float* __restrict__ x,
                                             const unsigned short* __restrict__ wqT,
                                             const float* __restrict__ b_qkv,
                                             unsigned short* __restrict__ qb,
                                             unsigned short* __restrict__ kb,
                                             unsigned short* __restrict__ vt) {
  __shared__ char lds[65536];   // sA[d]: d*8192 (8KB) ; sB[d]: 16384 + d*24576 (24KB)
  const int t = threadIdx.x;
  const int lane = t & 63, w = t >> 6;
  const int l15 = lane & 15, l4 = lane >> 4;
  const int wm = w >> 2, wn = w & 3;
  const int m0 = blockIdx.x * 64;

  // A staging geometry: thread owns 8 consecutive fp32 of one row
  const int arow = t >> 3;            // 0..63
  const int akc  = (t & 7) * 8;       // 0..56
  const float* xrow = x + (size_t)(m0 + arow) * 2048 + akc;
  const int aoff = arow * 128 + ((akc * 2) ^ ((arow & 7) << 4));

  f32x4 acc[2][3] = {};
  float4 a0, a1;

  auto issueA = [&](int kt) {
    a0 = *(const float4*)(xrow + kt * 64);
    a1 = *(const float4*)(xrow + kt * 64 + 4);
  };
  auto writeA = [&](int d) {
    u16x8 h;
    h[0] = f2bf(a0.x); h[1] = f2bf(a0.y); h[2] = f2bf(a0.z); h[3] = f2bf(a0.w);
    h[4] = f2bf(a1.x); h[5] = f2bf(a1.y); h[6] = f2bf(a1.z); h[7] = f2bf(a1.w);
    *(u16x8*)(lds + d * 8192 + aoff) = h;
  };
  auto stageB = [&](int kt, int d) {
    char* bbase = lds + 16384 + d * 24576;
#pragma unroll
    for (int p = 0; p < 3; ++p) {     // 24KB: 3 x (512 threads x 16B)
      int L = p * 8192 + (w << 10) + (lane << 4);
      int row = L >> 7;
      int cb = (L & 127) ^ ((row & 7) << 4);
      GLD16((const char*)wqT + (size_t)row * 4096 + kt * 128 + cb,
            bbase + p * 8192 + (w << 10));
    }
  };
  auto compute = [&](int d) {
    const char* aB = lds + d * 8192;
    const char* bB = lds + 16384 + d * 24576;
#pragma unroll
    for (int kk = 0; kk < 2; ++kk) {
      int cb = kk * 64 + l4 * 16;
      bf16x8 af[2], bfr[3];
#pragma unroll
      for (int m = 0; m < 2; ++m) {
        int r = wm * 32 + m * 16 + l15;
        af[m] = *(const bf16x8*)(aB + r * 128 + (cb ^ ((r & 7) << 4)));
      }
#pragma unroll
      for (int n = 0; n < 3; ++n) {
        int r = wn * 48 + n * 16 + l15;
        bfr[n] = *(const bf16x8*)(bB + r * 128 + (cb ^ ((r & 7) << 4)));
      }
#pragma unroll
      for (int m = 0; m < 2; ++m)
#pragma unroll
        for (int n = 0; n < 3; ++n)
          acc[m][n] = __builtin_amdgcn_mfma_f32_16x16x32_bf16(af[m], bfr[n], acc[m][n], 0, 0, 0);
    }
  };

  issueA(0); stageB(0, 0); writeA(0);
  __syncthreads();
  int d = 0;
  for (int kt = 0; kt < 32; ++kt) {
    if (kt < 31) { issueA(kt + 1); stageB(kt + 1, d ^ 1); }
    compute(d);
    if (kt < 31) writeA(d ^ 1);
    __syncthreads();                  // drains vmcnt (GLD) + lgkm, publishes writes
    d ^= 1;
  }

  // epilogue: C/D layout col=lane&15, row=(lane>>4)*4+reg
#pragma unroll
  for (int m = 0; m < 2; ++m)
#pragma unroll
    for (int n = 0; n < 3; ++n) {
      int c = wn * 48 + n * 16 + l15;   // 0..191
      int j = c >> 6, cc = c & 63;
      float bias = b_qkv[c];
#pragma unroll
      for (int r = 0; r < 4; ++r) {
        int grow = m0 + wm * 32 + m * 16 + l4 * 4 + r;
        unsigned short h = f2bf(acc[m][n][r] + bias);
        if (j == 0)      qb[(size_t)grow * 64 + cc] = h;
        else if (j == 1) kb[(size_t)grow * 64 + cc] = h;
        else {            // v stored transposed: [b][64][2048]
          int bbv = grow >> 11, nn = grow & 2047;
          vt[((size_t)bbv * 64 + cc) * 2048 + nn] = h;
        }
      }
    }
}

// ---------- 4. flash attention, KV-split x2, double-buffered K/V ----------
// grid (32 qtile, 8 batch, 2 kv-half). 4 waves x 16 q-rows. Writes fp32
// unnormalized partials + (m,l) per row; k_comb merges the two halves.
__global__ __launch_bounds__(256) void k_attn(const unsigned short* __restrict__ qb,
                                              const unsigned short* __restrict__ kb,
                                              const unsigned short* __restrict__ vt,
                                              float* __restrict__ ctxp,
                                              float* __restrict__ mlp) {
  __shared__ char lds[40960];  // sK[d]: d*8192 ; sV[d]: 16384+d*8192 ; sP: 32768+w*2048
  const int t = threadIdx.x;
  const int lane = t & 63, w = t >> 6;
  const int l15 = lane & 15, l4 = lane >> 4;
  const int bb = blockIdx.y;
  const int half = blockIdx.z;
  const int q0 = blockIdx.x * 64 + w * 16;
  const int kt0 = half * 16;
  const unsigned short* qrow = qb + ((size_t)bb * 2048 + q0 + l15) * 64;
  bf16x8 aq[2];
  aq[0] = *(const bf16x8*)(qrow + l4 * 8);   // A-frag: row=l&15, k=(l>>4)*8+j
  aq[1] = *(const bf16x8*)(qrow + 32 + l4 * 8);
  f32x4 ctx[4] = {};
  float mrow[4] = {-1e30f, -1e30f, -1e30f, -1e30f};
  float lrow[4] = {0.f, 0.f, 0.f, 0.f};
  const char* kBase = (const char*)kb + (size_t)bb * 2048 * 128;
  const char* vBase = (const char*)vt + (size_t)bb * 64 * 4096;
  char* pw = lds + 32768 + (w << 11);

  auto stage = [&](int kt, int d) {
#pragma unroll
    for (int p = 0; p < 2; ++p) {
      int L = p * 4096 + (w << 10) + (lane << 4);
      int row = L >> 7;
      int cb = (L & 127) ^ ((row & 7) << 4);
      GLD16(kBase + (size_t)(kt * 64 + row) * 128 + cb,
            lds + d * 8192 + p * 4096 + (w << 10));
      GLD16(vBase + (size_t)row * 4096 + kt * 128 + cb,
            lds + 16384 + d * 8192 + p * 4096 + (w << 10));
    }
  };

  stage(kt0, 0);
  __syncthreads();
  int d = 0;
  for (int kt = 0; kt < 16; ++kt) {
    if (kt < 15) stage(kt0 + kt + 1, d ^ 1);   // prefetch next tile
    const char* sK = lds + d * 8192;
    const char* sV = lds + 16384 + d * 8192;
    // S = Q K^T
    f32x4 s[4] = {};
#pragma unroll
    for (int kk = 0; kk < 2; ++kk) {
      int cb = kk * 64 + l4 * 16;
#pragma unroll
      for (int nf = 0; nf < 4; ++nf) {
        int r = nf * 16 + l15;
        bf16x8 bk = *(const bf16x8*)(sK + r * 128 + (cb ^ ((r & 7) << 4)));
        s[nf] = __builtin_amdgcn_mfma_f32_16x16x32_bf16(aq[kk], bk, s[nf], 0, 0, 0);
      }
    }
    // online softmax
#pragma unroll
    for (int r = 0; r < 4; ++r) {
      float cm = fmaxf(fmaxf(s[0][r], s[1][r]), fmaxf(s[2][r], s[3][r])) * 0.125f;
      cm = fmaxf(cm, __shfl_xor(cm, 1));
      cm = fmaxf(cm, __shfl_xor(cm, 2));
      cm = fmaxf(cm, __shfl_xor(cm, 4));
      cm = fmaxf(cm, __shfl_xor(cm, 8));
      float mn = fmaxf(mrow[r], cm);
      float alpha = __expf(mrow[r] - mn);
      mrow[r] = mn;
      float rs = 0.f;
#pragma unroll
      for (int nf = 0; nf < 4; ++nf) {
        float p = __expf(s[nf][r] * 0.125f - mn);
        s[nf][r] = p;
        rs += p;
      }
      rs += __shfl_xor(rs, 1); rs += __shfl_xor(rs, 2);
      rs += __shfl_xor(rs, 4); rs += __shfl_xor(rs, 8);
      lrow[r] = lrow[r] * alpha + rs;
#pragma unroll
      for (int nf = 0; nf < 4; ++nf) ctx[nf][r] *= alpha;
    }
    // P (D-layout) -> per-wave LDS (A-layout), bf16, swizzled
#pragma unroll
    for (int nf = 0; nf < 4; ++nf)
#pragma unroll
      for (int r = 0; r < 4; ++r) {
        int prow = l4 * 4 + r;
        int cbb = (nf * 16 + l15) * 2;
        *(unsigned short*)(pw + prow * 128 + (cbb ^ ((prow & 7) << 4))) = f2bf(s[nf][r]);
      }
    // ctx += P V
#pragma unroll
    for (int kk = 0; kk < 2; ++kk) {
      int cb = kk * 64 + l4 * 16;
      bf16x8 pa = *(const bf16x8*)(pw + l15 * 128 + (cb ^ ((l15 & 7) << 4)));
#pragma unroll
      for (int nf = 0; nf < 4; ++nf) {
        int rv = nf * 16 + l15;
        bf16x8 bv = *(const bf16x8*)(sV + rv * 128 + (cb ^ ((rv & 7) << 4)));
        ctx[nf] = __builtin_amdgcn_mfma_f32_16x16x32_bf16(pa, bv, ctx[nf], 0, 0, 0);
      }
    }
    __syncthreads();
    d ^= 1;
  }
  // write fp32 partials (unnormalized) + m,l
#pragma unroll
  for (int nf = 0; nf < 4; ++nf)
#pragma unroll
    for (int r = 0; r < 4; ++r) {
      size_t g = (size_t)bb * 2048 + q0 + l4 * 4 + r;
      ctxp[((size_t)half * 16384 + g) * 64 + nf * 16 + l15] = ctx[nf][r];
    }
  if (l15 == 0) {
#pragma unroll
    for (int r = 0; r < 4; ++r) {
      size_t g = (size_t)bb * 2048 + q0 + l4 * 4 + r;
      mlp[((size_t)half * 16384 + g) * 2 + 0] = mrow[r];
      mlp[((size_t)half * 16384 + g) * 2 + 1] = lrow[r];
    }
  }
}

// ---------- 5. combine the two KV halves -> bf16 ctx ----------
__global__ __launch_bounds__(256) void k_comb(const float* __restrict__ ctxp,
                                              const float* __restrict__ mlp,
                                              unsigned short* __restrict__ ctxb) {
  int idx = blockIdx.x * 256 + threadIdx.x;   // 16384*8
  int row = idx >> 3, c8 = (idx & 7) * 8;
  float m0 = mlp[(size_t)row * 2],              l0 = mlp[(size_t)row * 2 + 1];
  float m1 = mlp[((size_t)16384 + row) * 2],    l1 = mlp[((size_t)16384 + row) * 2 + 1];
  float M = fmaxf(m0, m1);
  float a0 = __expf(m0 - M), a1 = __expf(m1 - M);
  float inv = 1.0f / (l0 * a0 + l1 * a1);
  const float4* p0 = (const float4*)(ctxp + (size_t)row * 64 + c8);
  const float4* p1 = (const float4*)(ctxp + ((size_t)16384 + row) * 64 + c8);
  u16x8 o;
#pragma unroll
  for (int q = 0; q < 2; ++q) {
    float4 v0 = p0[q], v1 = p1[q];
    o[q * 4 + 0] = f2bf((v0.x * a0 + v1.x * a1) * inv);
    o[q * 4 + 1] = f2bf((v0.y * a0 + v1.y * a1) * inv);
    o[q * 4 + 2] = f2bf((v0.z * a0 + v1.z * a1) * inv);
    o[q * 4 + 3] = f2bf((v0.w * a0 + v1.w * a1) * inv);
  }
  *(u16x8*)(ctxb + (size_t)row * 64 + c8) = o;
}

// ---------- 6. proj GEMM: [16384,64] x [64,2048] + bias -> fp32 ----------
__global__ __launch_bounds__(256) void k_proj(const unsigned short* __restrict__ ctxb,
                                              const unsigned short* __restrict__ wpT,
                                              const float* __restrict__ b_proj,
                                              float* __restrict__ out) {
  __shared__ unsigned short sA[64 * 64];     // [row][k]
  __shared__ unsigned short sB[256 * 64];    // [n][k]
  const int t = threadIdx.x;
  const int lane = t & 63, w = t >> 6;
  const int l15 = lane & 15, l4 = lane >> 4;
  const int m0 = blockIdx.x * 64;
  const int n0 = blockIdx.y * 256;
#pragma unroll
  for (int p = 0; p < 2; ++p) {
    int L = p * 4096 + t * 16;
    int row = L >> 7;
    int cb = (L & 127) ^ ((row & 7) << 4);
    GLD16((const char*)ctxb + (size_t)(m0 + row) * 128 + cb,
          (char*)sA + p * 4096 + (w << 10));
  }
#pragma unroll
  for (int p = 0; p < 8; ++p) {
    int L = p * 4096 + t * 16;
    int row = L >> 7;
    int cb = (L & 127) ^ ((row & 7) << 4);
    GLD16((const char*)wpT + (size_t)(n0 + row) * 128 + cb,
          (char*)sB + p * 4096 + (w << 10));
  }
  __syncthreads();
  f32x4 acc[4][4] = {};
#pragma unroll
  for (int kk = 0; kk < 2; ++kk) {
    int cb = kk * 64 + l4 * 16;
    bf16x8 af[4], bfr[4];
#pragma unroll
    for (int m = 0; m < 4; ++m) {
      int r = m * 16 + l15;
      af[m] = *(const bf16x8*)((const char*)sA + r * 128 + (cb ^ ((r & 7) << 4)));
    }
#pragma unroll
    for (int n = 0; n < 4; ++n) {
      int r = w * 64 + n * 16 + l15;
      bfr[n] = *(const bf16x8*)((const char*)sB + r * 128 + (cb ^ ((r & 7) << 4)));
    }
#pragma unroll
    for (int m = 0; m < 4; ++m)
#pragma unroll
      for (int n = 0; n < 4; ++n)
        acc[m][n] = __builtin_amdgcn_mfma_f32_16x16x32_bf16(af[m], bfr[n], acc[m][n], 0, 0, 0);
  }
#pragma unroll
  for (int m = 0; m < 4; ++m)
#pragma unroll
    for (int n = 0; n < 4; ++n)
#pragma unroll
      for (int r = 0; r < 4; ++r) {
        int grow = m0 + m * 16 + l4 * 4 + r;
        int gcol = n0 + w * 64 + n * 16 + l15;
        out[(size_t)grow * 2048 + gcol] = acc[m][n][r] + b_proj[gcol];
      }
}

// ---------- launch ----------
extern "C" void kernel_launch(void* const* d_in, const int* in_sizes, int n_in,
                              void* d_out, int out_size, void* d_ws, size_t ws_size,
                              hipStream_t stream) {
  const float* x      = (const float*)d_in[0];
  const float* W_qkv  = (const float*)d_in[1];
  const float* b_qkv  = (const float*)d_in[2];
  const float* W_proj = (const float*)d_in[3];
  const float* b_proj = (const float*)d_in[4];
  float* out = (float*)d_out;

  unsigned short* ws   = (unsigned short*)d_ws;
  unsigned short* wqT  = ws;                                   // 192*2048
  unsigned short* wpT  = wqT + (size_t)192 * 2048;             // 2048*64
  unsigned short* qb   = wpT + (size_t)2048 * 64;              // 16384*64
  unsigned short* kb   = qb  + (size_t)16384 * 64;
  unsigned short* vt   = kb  + (size_t)16384 * 64;             // [8][64][2048]
  unsigned short* ctxb = vt  + (size_t)16384 * 64;             // 16384*64
  float* ctxp = (float*)(ctxb + (size_t)16384 * 64);           // [2][16384][64]
  float* mlp  = ctxp + (size_t)2 * 16384 * 64;                 // [2][16384][2]

  k_tr_wq<<<(192 * 2048) / 256, 256, 0, stream>>>(W_qkv, wqT);
  k_tr_wp<<<(2048 * 64) / 256, 256, 0, stream>>>(W_proj, wpT);
  k_qkv<<<256, 512, 0, stream>>>(x, wqT, b_qkv, qb, kb, vt);
  k_attn<<<dim3(32, 8, 2), 256, 0, stream>>>(qb, kb, vt, ctxp, mlp);
  k_comb<<<512, 256, 0, stream>>>(ctxp, mlp, ctxb);
  k_proj<<<dim3(256, 8), 256, 0, stream>>>(ctxb, wpT, b_proj, out);
}

// Round 3
// 111.896 us; speedup vs baseline: 1.5057x; 1.0648x over previous
//
#include <hip/hip_runtime.h>

// ---------- types ----------
typedef __bf16 bf16x8 __attribute__((ext_vector_type(8)));
typedef unsigned short u16x8 __attribute__((ext_vector_type(8)));
typedef unsigned short u16x4 __attribute__((ext_vector_type(4)));
typedef float  f32x4  __attribute__((ext_vector_type(4)));

#define QSCALE 0.1803368801111204f   // 0.125 * log2(e): S comes out in log2 domain

__device__ __forceinline__ unsigned short f2bf(float f) {
  unsigned int u = __float_as_uint(f);
  u = u + 0x7fffu + ((u >> 16) & 1u);   // RNE
  return (unsigned short)(u >> 16);
}

// global_load_lds, 16B per lane; LDS dest = wave-uniform base + lane*16
#define GLD16(src, dst)                                                        \
  __builtin_amdgcn_global_load_lds(                                            \
      (const __attribute__((address_space(1))) void*)(src),                    \
      (__attribute__((address_space(3))) void*)(dst), 16, 0, 0)

// All MFMA LDS tiles have 128-byte rows; swizzle: byte ^= (row&7)<<4 (both sides).

// ---------- 1. W_qkv [2048][192] -> bf16 W^T [192][2048], LDS-tiled ----------
__global__ __launch_bounds__(256) void k_tr_wq(const float* __restrict__ W,
                                               unsigned short* __restrict__ WT) {
  __shared__ float tile[64][193];
  const int t = threadIdx.x;
  const int k0 = blockIdx.x * 64;
#pragma unroll
  for (int i = 0; i < 12; ++i) {       // 64 rows x 48 float4
    int u = i * 256 + t;
    int row = u / 48, c4 = u % 48;
    float4 v = *(const float4*)(W + (size_t)(k0 + row) * 192 + c4 * 4);
    tile[row][c4 * 4 + 0] = v.x; tile[row][c4 * 4 + 1] = v.y;
    tile[row][c4 * 4 + 2] = v.z; tile[row][c4 * 4 + 3] = v.w;
  }
  __syncthreads();
#pragma unroll
  for (int i = 0; i < 6; ++i) {        // 192 cols x 8 u16x8
    int u = i * 256 + t;
    int c = u >> 3, k8 = (u & 7) * 8;
    u16x8 h;
#pragma unroll
    for (int j = 0; j < 8; ++j) h[j] = f2bf(tile[k8 + j][c]);
    *(u16x8*)(WT + (size_t)c * 2048 + k0 + k8) = h;
  }
}

// ---------- 2. W_proj [64][2048] -> bf16 W^T [2048][64], LDS-tiled ----------
__global__ __launch_bounds__(256) void k_tr_wp(const float* __restrict__ W,
                                               unsigned short* __restrict__ WT) {
  __shared__ float tile[64][65];
  const int t = threadIdx.x;
  const int n0 = blockIdx.x * 64;
#pragma unroll
  for (int i = 0; i < 4; ++i) {        // 64 rows x 16 float4
    int u = i * 256 + t;
    int d = u >> 4, c4 = u & 15;
    float4 v = *(const float4*)(W + (size_t)d * 2048 + n0 + c4 * 4);
    tile[d][c4 * 4 + 0] = v.x; tile[d][c4 * 4 + 1] = v.y;
    tile[d][c4 * 4 + 2] = v.z; tile[d][c4 * 4 + 3] = v.w;
  }
  __syncthreads();
#pragma unroll
  for (int i = 0; i < 2; ++i) {        // 64 n-rows x 8 u16x8
    int u = i * 256 + t;
    int n = u >> 3, d8 = (u & 7) * 8;
    u16x8 h;
#pragma unroll
    for (int j = 0; j < 8; ++j) h[j] = f2bf(tile[d8 + j][n0 ? n : n]);  // tile[d][n]
    // fix index: need tile[d8+j][n]
    h[0] = f2bf(tile[d8 + 0][n]); h[1] = f2bf(tile[d8 + 1][n]);
    h[2] = f2bf(tile[d8 + 2][n]); h[3] = f2bf(tile[d8 + 3][n]);
    h[4] = f2bf(tile[d8 + 4][n]); h[5] = f2bf(tile[d8 + 5][n]);
    h[6] = f2bf(tile[d8 + 6][n]); h[7] = f2bf(tile[d8 + 7][n]);
    *(u16x8*)(WT + (size_t)(n0 + n) * 64 + d8) = h;
  }
}

// ---------- 3. fused QKV GEMM: [16384,2048] x [2048,192] ----------
// BM=64, BN=192 (q|k|v), BK=64. 512 threads = 8 waves (2M x 4N), grid 256.
__global__ __launch_bounds__(512) void k_qkv(const float* __restrict__ x,
                                             const unsigned short* __restrict__ wqT,
                                             const float* __restrict__ b_qkv,
                                             unsigned short* __restrict__ qb,
                                             unsigned short* __restrict__ kb,
                                             unsigned short* __restrict__ vt) {
  __shared__ __align__(16) char lds[65536];  // sA[d]: d*8192 ; sB[d]: 16384+d*24576
  const int t = threadIdx.x;
  const int lane = t & 63, w = t >> 6;
  const int l15 = lane & 15, l4 = lane >> 4;
  const int wm = w >> 2, wn = w & 3;
  const int m0 = blockIdx.x * 64;

  const int arow = t >> 3;            // 0..63
  const int akc  = (t & 7) * 8;       // 0..56
  const float* xrow = x + (size_t)(m0 + arow) * 2048 + akc;
  const int aoff = arow * 128 + ((akc * 2) ^ ((arow & 7) << 4));

  f32x4 acc[2][3] = {};
  float4 a0, a1;

  auto issueA = [&](int kt) {
    a0 = *(const float4*)(xrow + kt * 64);
    a1 = *(const float4*)(xrow + kt * 64 + 4);
  };
  auto writeA = [&](int d) {
    u16x8 h;
    h[0] = f2bf(a0.x); h[1] = f2bf(a0.y); h[2] = f2bf(a0.z); h[3] = f2bf(a0.w);
    h[4] = f2bf(a1.x); h[5] = f2bf(a1.y); h[6] = f2bf(a1.z); h[7] = f2bf(a1.w);
    *(u16x8*)(lds + d * 8192 + aoff) = h;
  };
  auto stageB = [&](int kt, int d) {
    char* bbase = lds + 16384 + d * 24576;
#pragma unroll
    for (int p = 0; p < 3; ++p) {
      int L = p * 8192 + (w << 10) + (lane << 4);
      int row = L >> 7;
      int cb = (L & 127) ^ ((row & 7) << 4);
      GLD16((const char*)wqT + (size_t)row * 4096 + kt * 128 + cb,
            bbase + p * 8192 + (w << 10));
    }
  };
  auto compute = [&](int d) {
    const char* aB = lds + d * 8192;
    const char* bB = lds + 16384 + d * 24576;
#pragma unroll
    for (int kk = 0; kk < 2; ++kk) {
      int cb = kk * 64 + l4 * 16;
      bf16x8 af[2], bfr[3];
#pragma unroll
      for (int m = 0; m < 2; ++m) {
        int r = wm * 32 + m * 16 + l15;
        af[m] = *(const bf16x8*)(aB + r * 128 + (cb ^ ((r & 7) << 4)));
      }
#pragma unroll
      for (int n = 0; n < 3; ++n) {
        int r = wn * 48 + n * 16 + l15;
        bfr[n] = *(const bf16x8*)(bB + r * 128 + (cb ^ ((r & 7) << 4)));
      }
#pragma unroll
      for (int m = 0; m < 2; ++m)
#pragma unroll
        for (int n = 0; n < 3; ++n)
          acc[m][n] = __builtin_amdgcn_mfma_f32_16x16x32_bf16(af[m], bfr[n], acc[m][n], 0, 0, 0);
    }
  };

  issueA(0); stageB(0, 0); writeA(0);
  __syncthreads();
  int d = 0;
  for (int kt = 0; kt < 32; ++kt) {
    if (kt < 31) { issueA(kt + 1); stageB(kt + 1, d ^ 1); }
    compute(d);
    if (kt < 31) writeA(d ^ 1);
    __syncthreads();
    d ^= 1;
  }

  // epilogue: C/D layout col=lane&15, row=(lane>>4)*4+reg
#pragma unroll
  for (int m = 0; m < 2; ++m)
#pragma unroll
    for (int n = 0; n < 3; ++n) {
      int c = wn * 48 + n * 16 + l15;   // 0..191
      int j = c >> 6, cc = c & 63;
      float bias = b_qkv[c];
      int grow0 = m0 + wm * 32 + m * 16 + l4 * 4;
      if (j == 0) {
#pragma unroll
        for (int r = 0; r < 4; ++r)
          qb[(size_t)(grow0 + r) * 64 + cc] = f2bf((acc[m][n][r] + bias) * QSCALE);
      } else if (j == 1) {
#pragma unroll
        for (int r = 0; r < 4; ++r)
          kb[(size_t)(grow0 + r) * 64 + cc] = f2bf(acc[m][n][r] + bias);
      } else {            // v transposed: [b][64][2048]; 4 consecutive nn -> 8B store
        int bbv = grow0 >> 11, nn0 = grow0 & 2047;
        u16x4 h;
        h[0] = f2bf(acc[m][n][0] + bias); h[1] = f2bf(acc[m][n][1] + bias);
        h[2] = f2bf(acc[m][n][2] + bias); h[3] = f2bf(acc[m][n][3] + bias);
        *(u16x4*)(vt + ((size_t)bbv * 64 + cc) * 2048 + nn0) = h;
      }
    }
}

// ---------- 4. flash attention, swapped-operand (S^T), KV-split x2 ----------
// grid (32 qtile, 8 batch, 2 kv-half). 4 waves x 16 q-rows (q = lane&15).
__global__ __launch_bounds__(256) void k_attn(const unsigned short* __restrict__ qb,
                                              const unsigned short* __restrict__ kb,
                                              const unsigned short* __restrict__ vt,
                                              float* __restrict__ ctxp,
                                              float* __restrict__ mlp) {
  __shared__ __align__(16) char lds[32768];  // sK[d]: d*8192 ; sV[d]: 16384+d*8192
  const int t = threadIdx.x;
  const int lane = t & 63, w = t >> 6;
  const int l15 = lane & 15, l4 = lane >> 4;
  const int bb = blockIdx.y;
  const int half = blockIdx.z;
  const int q0 = blockIdx.x * 64 + w * 16;
  const int kt0 = half * 16;
  const unsigned short* qrow = qb + ((size_t)bb * 2048 + q0 + l15) * 64;
  bf16x8 aq[2];
  aq[0] = *(const bf16x8*)(qrow + l4 * 8);       // B-frag: col=l15(q), k=(l>>4)*8+j
  aq[1] = *(const bf16x8*)(qrow + 32 + l4 * 8);
  f32x4 ctx[4] = {};                              // ctx^T: q=l15, d=df*16+l4*4+r
  float m = -1e30f, lsum = 0.f;
  const char* kBase = (const char*)kb + (size_t)bb * 2048 * 128;
  const char* vBase = (const char*)vt + (size_t)bb * 64 * 4096;
  const int srcA = ((l4 & 1) << 5) | l15;         // lane 2*(l4&1)*16 + l15
  const int srcB = srcA + 16;
  const bool hi = (l4 >> 1) & 1;

  auto stage = [&](int kt, int d) {
#pragma unroll
    for (int p = 0; p < 2; ++p) {
      int L = p * 4096 + (w << 10) + (lane << 4);
      int row = L >> 7;
      int cb = (L & 127) ^ ((row & 7) << 4);
      GLD16(kBase + (size_t)(kt * 64 + row) * 128 + cb,
            lds + d * 8192 + p * 4096 + (w << 10));
      GLD16(vBase + (size_t)row * 4096 + kt * 128 + cb,
            lds + 16384 + d * 8192 + p * 4096 + (w << 10));
    }
  };

  stage(kt0, 0);
  __syncthreads();
  int d = 0;
  for (int kt = 0; kt < 16; ++kt) {
    if (kt < 15) stage(kt0 + kt + 1, d ^ 1);
    const char* sK = lds + d * 8192;
    const char* sV = lds + 16384 + d * 8192;
    // S^T = K Q^T : s[mf] holds q=l15, kv = mf*16 + l4*4 + r  (log2-domain scores)
    f32x4 s[4] = {};
    __builtin_amdgcn_s_setprio(1);
#pragma unroll
    for (int kk = 0; kk < 2; ++kk) {
      int cb = kk * 64 + l4 * 16;
#pragma unroll
      for (int mf = 0; mf < 4; ++mf) {
        int r = mf * 16 + l15;
        bf16x8 kf = *(const bf16x8*)(sK + r * 128 + (cb ^ ((r & 7) << 4)));
        s[mf] = __builtin_amdgcn_mfma_f32_16x16x32_bf16(kf, aq[kk], s[mf], 0, 0, 0);
      }
    }
    __builtin_amdgcn_s_setprio(0);
    // in-lane max over 16, then 2 shuffles across l4 groups
    float pm = fmaxf(fmaxf(fmaxf(s[0][0], s[0][1]), fmaxf(s[0][2], s[0][3])),
                     fmaxf(fmaxf(s[1][0], s[1][1]), fmaxf(s[1][2], s[1][3])));
    pm = fmaxf(pm, fmaxf(fmaxf(fmaxf(s[2][0], s[2][1]), fmaxf(s[2][2], s[2][3])),
                         fmaxf(fmaxf(s[3][0], s[3][1]), fmaxf(s[3][2], s[3][3]))));
    pm = fmaxf(pm, __shfl_xor(pm, 16));
    pm = fmaxf(pm, __shfl_xor(pm, 32));
    if (!__all(pm <= m + 11.5f)) {     // T13 defer-max (log2 domain, thr = 8*log2e)
      float mn = fmaxf(m, pm);
      float al = __builtin_exp2f(m - mn);
      m = mn; lsum *= al;
#pragma unroll
      for (int df = 0; df < 4; ++df)
#pragma unroll
        for (int r = 0; r < 4; ++r) ctx[df][r] *= al;
    }
    float lp = 0.f;
#pragma unroll
    for (int mf = 0; mf < 4; ++mf)
#pragma unroll
      for (int r = 0; r < 4; ++r) {
        float p = __builtin_exp2f(s[mf][r] - m);
        s[mf][r] = p;
        lp += p;
      }
    lsum += lp;                        // cross-l4 sum deferred to the end
    // pack P^T to bf16 pairs
    unsigned int pk[4][2];
#pragma unroll
    for (int mf = 0; mf < 4; ++mf) {
      asm("v_cvt_pk_bf16_f32 %0, %1, %2" : "=v"(pk[mf][0]) : "v"(s[mf][0]), "v"(s[mf][1]));
      asm("v_cvt_pk_bf16_f32 %0, %1, %2" : "=v"(pk[mf][1]) : "v"(s[mf][2]), "v"(s[mf][3]));
    }
    // ctx^T += V^T P^T
#pragma unroll
    for (int kk = 0; kk < 2; ++kk) {
      unsigned int q00 = __shfl((int)pk[2 * kk][0], srcA);
      unsigned int q10 = __shfl((int)pk[2 * kk + 1][0], srcA);
      unsigned int q01 = __shfl((int)pk[2 * kk][1], srcA);
      unsigned int q11 = __shfl((int)pk[2 * kk + 1][1], srcA);
      unsigned int r00 = __shfl((int)pk[2 * kk][0], srcB);
      unsigned int r10 = __shfl((int)pk[2 * kk + 1][0], srcB);
      unsigned int r01 = __shfl((int)pk[2 * kk][1], srcB);
      unsigned int r11 = __shfl((int)pk[2 * kk + 1][1], srcB);
      uint4 uu;
      uu.x = hi ? q10 : q00;
      uu.y = hi ? q11 : q01;
      uu.z = hi ? r10 : r00;
      uu.w = hi ? r11 : r01;
      bf16x8 pfrag = *(bf16x8*)&uu;
      int cb = kk * 64 + l4 * 16;
      __builtin_amdgcn_s_setprio(1);
#pragma unroll
      for (int df = 0; df < 4; ++df) {
        int rv = df * 16 + l15;
        bf16x8 vf = *(const bf16x8*)(sV + rv * 128 + (cb ^ ((rv & 7) << 4)));
        ctx[df] = __builtin_amdgcn_mfma_f32_16x16x32_bf16(vf, pfrag, ctx[df], 0, 0, 0);
      }
      __builtin_amdgcn_s_setprio(0);
    }
    __syncthreads();
    d ^= 1;
  }
  lsum += __shfl_xor(lsum, 16);
  lsum += __shfl_xor(lsum, 32);
  // write fp32 unnormalized partials (float4: 4 consecutive d) + (m, lsum)
  size_t g = (size_t)bb * 2048 + q0 + l15;
#pragma unroll
  for (int df = 0; df < 4; ++df) {
    f32x4 c = ctx[df];
    *(float4*)(ctxp + ((size_t)half * 16384 + g) * 64 + df * 16 + l4 * 4) =
        *(float4*)&c;
  }
  if (l4 == 0) {
    float2 ml = make_float2(m, lsum);
    *(float2*)(mlp + ((size_t)half * 16384 + g) * 2) = ml;
  }
}

// ---------- 5. proj GEMM fused with KV-half combine ----------
// grid (256 m-blocks, 8 n-blocks). BM=64, BN=256, K=64. 256 thr = 4 waves.
__global__ __launch_bounds__(256) void k_proj(const float* __restrict__ ctxp,
                                              const float* __restrict__ mlp,
                                              const unsigned short* __restrict__ wpT,
                                              const float* __restrict__ b_proj,
                                              float* __restrict__ out) {
  __shared__ __align__(16) char lds[40960];   // sA: 0..8KB ; sB: 8192..40KB
  const int t = threadIdx.x;
  const int lane = t & 63, w = t >> 6;
  const int l15 = lane & 15, l4 = lane >> 4;
  const int m0 = blockIdx.x * 64;
  const int n0 = blockIdx.y * 256;

  // stage sA: combine two halves -> bf16 [64][64], swizzled
  {
    int r_ = t >> 2;
    int dq = (t & 3) << 4;               // 16 d values
    size_t g = (size_t)m0 + r_;
    float m0v = mlp[g * 2], l0v = mlp[g * 2 + 1];
    float m1v = mlp[((size_t)16384 + g) * 2], l1v = mlp[((size_t)16384 + g) * 2 + 1];
    float M = fmaxf(m0v, m1v);
    float a0 = __builtin_exp2f(m0v - M), a1 = __builtin_exp2f(m1v - M);
    float inv = 1.0f / (l0v * a0 + l1v * a1);
    a0 *= inv; a1 *= inv;
    const float4* h0 = (const float4*)(ctxp + g * 64 + dq);
    const float4* h1 = (const float4*)(ctxp + ((size_t)16384 + g) * 64 + dq);
    int sw = (r_ & 7) << 4;
#pragma unroll
    for (int q = 0; q < 2; ++q) {
      float4 v0a = h0[q * 2], v0b = h0[q * 2 + 1];
      float4 v1a = h1[q * 2], v1b = h1[q * 2 + 1];
      u16x8 o;
      o[0] = f2bf(v0a.x * a0 + v1a.x * a1); o[1] = f2bf(v0a.y * a0 + v1a.y * a1);
      o[2] = f2bf(v0a.z * a0 + v1a.z * a1); o[3] = f2bf(v0a.w * a0 + v1a.w * a1);
      o[4] = f2bf(v0b.x * a0 + v1b.x * a1); o[5] = f2bf(v0b.y * a0 + v1b.y * a1);
      o[6] = f2bf(v0b.z * a0 + v1b.z * a1); o[7] = f2bf(v0b.w * a0 + v1b.w * a1);
      *(u16x8*)(lds + r_ * 128 + ((dq * 2 + q * 16) ^ sw)) = o;
    }
  }
  // stage sB: wpT rows n0..n0+255 (full K=64 row = 128B each)
#pragma unroll
  for (int p = 0; p < 8; ++p) {
    int L = p * 4096 + t * 16;
    int row = L >> 7;
    int cb = (L & 127) ^ ((row & 7) << 4);
    GLD16((const char*)wpT + (size_t)(n0 + row) * 128 + cb,
          lds + 8192 + p * 4096 + (w << 10));
  }
  __syncthreads();

  f32x4 acc[4][4] = {};
#pragma unroll
  for (int kk = 0; kk < 2; ++kk) {
    int cb = kk * 64 + l4 * 16;
    bf16x8 af[4], bfr[4];
#pragma unroll
    for (int m = 0; m < 4; ++m) {
      int r = m * 16 + l15;
      af[m] = *(const bf16x8*)(lds + r * 128 + (cb ^ ((r & 7) << 4)));
    }
#pragma unroll
    for (int n = 0; n < 4; ++n) {
      int r = w * 64 + n * 16 + l15;
      bfr[n] = *(const bf16x8*)(lds + 8192 + r * 128 + (cb ^ ((r & 7) << 4)));
    }
    // swapped: D col = ctx-row (out row), D row = wp-row (out col)
#pragma unroll
    for (int m = 0; m < 4; ++m)
#pragma unroll
      for (int n = 0; n < 4; ++n)
        acc[m][n] = __builtin_amdgcn_mfma_f32_16x16x32_bf16(bfr[n], af[m], acc[m][n], 0, 0, 0);
  }
#pragma unroll
  for (int m = 0; m < 4; ++m)
#pragma unroll
    for (int n = 0; n < 4; ++n) {
      int grow = m0 + m * 16 + l15;
      int gcol = n0 + w * 64 + n * 16 + l4 * 4;
      float4 bias = *(const float4*)(b_proj + gcol);
      float4 o;
      o.x = acc[m][n][0] + bias.x; o.y = acc[m][n][1] + bias.y;
      o.z = acc[m][n][2] + bias.z; o.w = acc[m][n][3] + bias.w;
      *(float4*)(out + (size_t)grow * 2048 + gcol) = o;
    }
}

// ---------- launch ----------
extern "C" void kernel_launch(void* const* d_in, const int* in_sizes, int n_in,
                              void* d_out, int out_size, void* d_ws, size_t ws_size,
                              hipStream_t stream) {
  const float* x      = (const float*)d_in[0];
  const float* W_qkv  = (const float*)d_in[1];
  const float* b_qkv  = (const float*)d_in[2];
  const float* W_proj = (const float*)d_in[3];
  const float* b_proj = (const float*)d_in[4];
  float* out = (float*)d_out;

  unsigned short* ws   = (unsigned short*)d_ws;
  unsigned short* wqT  = ws;                                   // 192*2048
  unsigned short* wpT  = wqT + (size_t)192 * 2048;             // 2048*64
  unsigned short* qb   = wpT + (size_t)2048 * 64;              // 16384*64 (pre-scaled)
  unsigned short* kb   = qb  + (size_t)16384 * 64;
  unsigned short* vt   = kb  + (size_t)16384 * 64;             // [8][64][2048]
  float* ctxp = (float*)(vt + (size_t)16384 * 64);             // [2][16384][64] fp32
  float* mlp  = ctxp + (size_t)2 * 16384 * 64;                 // [2][16384][2]

  k_tr_wq<<<32, 256, 0, stream>>>(W_qkv, wqT);
  k_tr_wp<<<32, 256, 0, stream>>>(W_proj, wpT);
  k_qkv<<<256, 512, 0, stream>>>(x, wqT, b_qkv, qb, kb, vt);
  k_attn<<<dim3(32, 8, 2), 256, 0, stream>>>(qb, kb, vt, ctxp, mlp);
  k_proj<<<dim3(256, 8), 256, 0, stream>>>(ctxp, mlp, wpT, b_proj, out);
}

// Round 4
// 104.518 us; speedup vs baseline: 1.6120x; 1.0706x over previous
//
#include <hip/hip_runtime.h>

// ---------- types ----------
typedef __bf16 bf16x8 __attribute__((ext_vector_type(8)));
typedef unsigned short u16x8 __attribute__((ext_vector_type(8)));
typedef unsigned short u16x4 __attribute__((ext_vector_type(4)));
typedef float  f32x4  __attribute__((ext_vector_type(4)));

#define QSCALE 0.1803368801111204f   // 0.125 * log2(e): S comes out in log2 domain

__device__ __forceinline__ unsigned short f2bf(float f) {
  unsigned int u = __float_as_uint(f);
  u = u + 0x7fffu + ((u >> 16) & 1u);   // RNE
  return (unsigned short)(u >> 16);
}

// global_load_lds, 16B per lane; LDS dest = wave-uniform base + lane*16
#define GLD16(src, dst)                                                        \
  __builtin_amdgcn_global_load_lds(                                            \
      (const __attribute__((address_space(1))) void*)(src),                    \
      (__attribute__((address_space(3))) void*)(dst), 16, 0, 0)

// All MFMA LDS tiles have 128-byte rows; swizzle: byte ^= (row&7)<<4 (both sides).

// ---------- 1. merged weight transposes ----------
// blocks 0..31: W_qkv [2048][192] -> bf16 wqT [192][2048]
// blocks 32..63: W_proj [64][2048] -> bf16 wpT [2048][64]
__global__ __launch_bounds__(256) void k_trw(const float* __restrict__ Wq,
                                             const float* __restrict__ Wp,
                                             unsigned short* __restrict__ wqT,
                                             unsigned short* __restrict__ wpT) {
  __shared__ float tile[64][193];
  const int t = threadIdx.x;
  if (blockIdx.x < 32) {
    const int k0 = blockIdx.x * 64;
#pragma unroll
    for (int i = 0; i < 12; ++i) {       // 64 rows x 48 float4
      int u = i * 256 + t;
      int row = u / 48, c4 = u % 48;
      float4 v = *(const float4*)(Wq + (size_t)(k0 + row) * 192 + c4 * 4);
      tile[row][c4 * 4 + 0] = v.x; tile[row][c4 * 4 + 1] = v.y;
      tile[row][c4 * 4 + 2] = v.z; tile[row][c4 * 4 + 3] = v.w;
    }
    __syncthreads();
#pragma unroll
    for (int i = 0; i < 6; ++i) {        // 192 cols x 8 u16x8
      int u = i * 256 + t;
      int c = u >> 3, k8 = (u & 7) * 8;
      u16x8 h;
#pragma unroll
      for (int j = 0; j < 8; ++j) h[j] = f2bf(tile[k8 + j][c]);
      *(u16x8*)(wqT + (size_t)c * 2048 + k0 + k8) = h;
    }
  } else {
    const int n0 = (blockIdx.x - 32) * 64;
#pragma unroll
    for (int i = 0; i < 4; ++i) {        // 64 d-rows x 16 float4
      int u = i * 256 + t;
      int dd = u >> 4, c4 = u & 15;
      float4 v = *(const float4*)(Wp + (size_t)dd * 2048 + n0 + c4 * 4);
      tile[dd][c4 * 4 + 0] = v.x; tile[dd][c4 * 4 + 1] = v.y;
      tile[dd][c4 * 4 + 2] = v.z; tile[dd][c4 * 4 + 3] = v.w;
    }
    __syncthreads();
#pragma unroll
    for (int i = 0; i < 2; ++i) {        // 64 n-rows x 8 u16x8
      int u = i * 256 + t;
      int n = u >> 3, d8 = (u & 7) * 8;
      u16x8 h;
      h[0] = f2bf(tile[d8 + 0][n]); h[1] = f2bf(tile[d8 + 1][n]);
      h[2] = f2bf(tile[d8 + 2][n]); h[3] = f2bf(tile[d8 + 3][n]);
      h[4] = f2bf(tile[d8 + 4][n]); h[5] = f2bf(tile[d8 + 5][n]);
      h[6] = f2bf(tile[d8 + 6][n]); h[7] = f2bf(tile[d8 + 7][n]);
      *(u16x8*)(wpT + (size_t)(n0 + n) * 64 + d8) = h;
    }
  }
}

// ---------- 2. fused QKV GEMM: [16384,2048] x [2048,192] ----------
// BM=64, BN=192 (q|k|v), BK=64. 512 threads = 8 waves (2M x 4N), grid 256.
// Counted-vmcnt pipeline: x prefetched 2 steps ahead (regs), B 1 step (GLD16).
__global__ __launch_bounds__(512) void k_qkv(const float* __restrict__ x,
                                             const unsigned short* __restrict__ wqT,
                                             const float* __restrict__ b_qkv,
                                             unsigned short* __restrict__ qb,
                                             unsigned short* __restrict__ kb,
                                             unsigned short* __restrict__ vt) {
  __shared__ __align__(16) char lds[65536];  // sA[d]: d*8192 ; sB[d]: 16384+d*24576
  const int t = threadIdx.x;
  const int lane = t & 63, w = t >> 6;
  const int l15 = lane & 15, l4 = lane >> 4;
  const int wm = w >> 2, wn = w & 3;
  const int m0 = blockIdx.x * 64;

  const int arow = t >> 3;            // 0..63
  const int akc  = (t & 7) * 8;       // 0..56
  const float* xrow = x + (size_t)(m0 + arow) * 2048 + akc;
  const int aoff = arow * 128 + ((akc * 2) ^ ((arow & 7) << 4));

  f32x4 acc[2][3] = {};
  float4 xa0_0, xa1_0, xa0_1, xa1_1;   // 2-deep x prefetch, parity = kt&1

  auto issueA_0 = [&](int kt) {
    xa0_0 = *(const float4*)(xrow + kt * 64);
    xa1_0 = *(const float4*)(xrow + kt * 64 + 4);
  };
  auto issueA_1 = [&](int kt) {
    xa0_1 = *(const float4*)(xrow + kt * 64);
    xa1_1 = *(const float4*)(xrow + kt * 64 + 4);
  };
  auto writeA_0 = [&]() {
    u16x8 h;
    h[0] = f2bf(xa0_0.x); h[1] = f2bf(xa0_0.y); h[2] = f2bf(xa0_0.z); h[3] = f2bf(xa0_0.w);
    h[4] = f2bf(xa1_0.x); h[5] = f2bf(xa1_0.y); h[6] = f2bf(xa1_0.z); h[7] = f2bf(xa1_0.w);
    *(u16x8*)(lds + 0 * 8192 + aoff) = h;
  };
  auto writeA_1 = [&]() {
    u16x8 h;
    h[0] = f2bf(xa0_1.x); h[1] = f2bf(xa0_1.y); h[2] = f2bf(xa0_1.z); h[3] = f2bf(xa0_1.w);
    h[4] = f2bf(xa1_1.x); h[5] = f2bf(xa1_1.y); h[6] = f2bf(xa1_1.z); h[7] = f2bf(xa1_1.w);
    *(u16x8*)(lds + 1 * 8192 + aoff) = h;
  };
  auto stageB = [&](int kt, int d) {
    char* bbase = lds + 16384 + d * 24576;
#pragma unroll
    for (int p = 0; p < 3; ++p) {
      int L = p * 8192 + (w << 10) + (lane << 4);
      int row = L >> 7;
      int cb = (L & 127) ^ ((row & 7) << 4);
      GLD16((const char*)wqT + (size_t)row * 4096 + kt * 128 + cb,
            bbase + p * 8192 + (w << 10));
    }
  };
  auto compute = [&](int d) {
    const char* aB = lds + d * 8192;
    const char* bB = lds + 16384 + d * 24576;
    __builtin_amdgcn_s_setprio(1);
#pragma unroll
    for (int kk = 0; kk < 2; ++kk) {
      int cb = kk * 64 + l4 * 16;
      bf16x8 af[2], bfr[3];
#pragma unroll
      for (int m = 0; m < 2; ++m) {
        int r = wm * 32 + m * 16 + l15;
        af[m] = *(const bf16x8*)(aB + r * 128 + (cb ^ ((r & 7) << 4)));
      }
#pragma unroll
      for (int n = 0; n < 3; ++n) {
        int r = wn * 48 + n * 16 + l15;
        bfr[n] = *(const bf16x8*)(bB + r * 128 + (cb ^ ((r & 7) << 4)));
      }
#pragma unroll
      for (int m = 0; m < 2; ++m)
#pragma unroll
        for (int n = 0; n < 3; ++n)
          acc[m][n] = __builtin_amdgcn_mfma_f32_16x16x32_bf16(af[m], bfr[n], acc[m][n], 0, 0, 0);
    }
    __builtin_amdgcn_s_setprio(0);
  };

  // FIFO accounting per step n (steady): entering, outstanding = [A(n+1)2, B(n)3].
  // writeA auto-drains A(n); +A(n+2)2 +B(n+1)3 -> vmcnt(5) drains A(n+1),B(n).
#define QKV_STEP(n, P, DOI, DOS, W)                                    \
  {                                                                    \
    writeA_##P();                                                      \
    if (DOI) issueA_##P((n) + 2);                                      \
    if (DOS) stageB((n) + 1, (P) ^ 1);                                 \
    asm volatile("s_waitcnt vmcnt(" W ") lgkmcnt(0)" ::: "memory");    \
    __builtin_amdgcn_s_barrier();                                      \
    compute(P);                                                        \
    __builtin_amdgcn_s_barrier();                                      \
  }

  issueA_0(0); issueA_1(1); stageB(0, 0);
  for (int kt = 0; kt < 30; kt += 2) {
    QKV_STEP(kt,     0, true, true, "5");
    QKV_STEP(kt + 1, 1, true, true, "5");
  }
  QKV_STEP(30, 0, false, true,  "5");
  QKV_STEP(31, 1, false, false, "0");
#undef QKV_STEP

  // epilogue: C/D layout col=lane&15, row=(lane>>4)*4+reg
#pragma unroll
  for (int m = 0; m < 2; ++m)
#pragma unroll
    for (int n = 0; n < 3; ++n) {
      int c = wn * 48 + n * 16 + l15;   // 0..191
      int j = c >> 6, cc = c & 63;
      float bias = b_qkv[c];
      int grow0 = m0 + wm * 32 + m * 16 + l4 * 4;
      if (j == 0) {
#pragma unroll
        for (int r = 0; r < 4; ++r)
          qb[(size_t)(grow0 + r) * 64 + cc] = f2bf((acc[m][n][r] + bias) * QSCALE);
      } else if (j == 1) {
#pragma unroll
        for (int r = 0; r < 4; ++r)
          kb[(size_t)(grow0 + r) * 64 + cc] = f2bf(acc[m][n][r] + bias);
      } else {            // v transposed: [b][64][2048]; 4 consecutive nn -> 8B store
        int bbv = grow0 >> 11, nn0 = grow0 & 2047;
        u16x4 h;
        h[0] = f2bf(acc[m][n][0] + bias); h[1] = f2bf(acc[m][n][1] + bias);
        h[2] = f2bf(acc[m][n][2] + bias); h[3] = f2bf(acc[m][n][3] + bias);
        *(u16x4*)(vt + ((size_t)bbv * 64 + cc) * 2048 + nn0) = h;
      }
    }
}

// ---------- 3. flash attention, swapped-operand (S^T), KV-split x2 ----------
// grid (32 qtile, 8 batch, 2 kv-half). 4 waves x 16 q-rows (q = lane&15).
// Counted-vmcnt: per-iter 4 GLDs; vmcnt(4) pre-compute barrier keeps prefetch in flight.
__global__ __launch_bounds__(256) void k_attn(const unsigned short* __restrict__ qb,
                                              const unsigned short* __restrict__ kb,
                                              const unsigned short* __restrict__ vt,
                                              float* __restrict__ ctxp,
                                              float* __restrict__ mlp) {
  __shared__ __align__(16) char lds[32768];  // sK[d]: d*8192 ; sV[d]: 16384+d*8192
  const int t = threadIdx.x;
  const int lane = t & 63, w = t >> 6;
  const int l15 = lane & 15, l4 = lane >> 4;
  const int bb = blockIdx.y;
  const int half = blockIdx.z;
  const int q0 = blockIdx.x * 64 + w * 16;
  const int kt0 = half * 16;
  const unsigned short* qrow = qb + ((size_t)bb * 2048 + q0 + l15) * 64;
  bf16x8 aq[2];
  aq[0] = *(const bf16x8*)(qrow + l4 * 8);       // B-frag: col=l15(q), k=(l>>4)*8+j
  aq[1] = *(const bf16x8*)(qrow + 32 + l4 * 8);
  f32x4 ctx[4] = {};                              // ctx^T: q=l15, d=df*16+l4*4+r
  float m = -1e30f, lsum = 0.f;
  const char* kBase = (const char*)kb + (size_t)bb * 2048 * 128;
  const char* vBase = (const char*)vt + (size_t)bb * 64 * 4096;
  const int srcA = ((l4 & 1) << 5) | l15;         // lane 2*(l4&1)*16 + l15
  const int srcB = srcA + 16;
  const bool hi = (l4 >> 1) & 1;

  auto stage = [&](int kt, int d) {
#pragma unroll
    for (int p = 0; p < 2; ++p) {
      int L = p * 4096 + (w << 10) + (lane << 4);
      int row = L >> 7;
      int cb = (L & 127) ^ ((row & 7) << 4);
      GLD16(kBase + (size_t)(kt * 64 + row) * 128 + cb,
            lds + d * 8192 + p * 4096 + (w << 10));
      GLD16(vBase + (size_t)row * 4096 + kt * 128 + cb,
            lds + 16384 + d * 8192 + p * 4096 + (w << 10));
    }
  };

  stage(kt0, 0);
  int d = 0;
  for (int kt = 0; kt < 16; ++kt) {
    if (kt < 15) {
      stage(kt0 + kt + 1, d ^ 1);
      asm volatile("s_waitcnt vmcnt(4)" ::: "memory");   // drains tile kt, keeps prefetch
    } else {
      asm volatile("s_waitcnt vmcnt(0)" ::: "memory");
    }
    __builtin_amdgcn_s_barrier();
    const char* sK = lds + d * 8192;
    const char* sV = lds + 16384 + d * 8192;
    // S^T = K Q^T : s[mf] holds q=l15, kv = mf*16 + l4*4 + r  (log2-domain scores)
    f32x4 s[4] = {};
    __builtin_amdgcn_s_setprio(1);
#pragma unroll
    for (int kk = 0; kk < 2; ++kk) {
      int cb = kk * 64 + l4 * 16;
#pragma unroll
      for (int mf = 0; mf < 4; ++mf) {
        int r = mf * 16 + l15;
        bf16x8 kf = *(const bf16x8*)(sK + r * 128 + (cb ^ ((r & 7) << 4)));
        s[mf] = __builtin_amdgcn_mfma_f32_16x16x32_bf16(kf, aq[kk], s[mf], 0, 0, 0);
      }
    }
    __builtin_amdgcn_s_setprio(0);
    // in-lane max over 16, then 2 shuffles across l4 groups
    float pm = fmaxf(fmaxf(fmaxf(s[0][0], s[0][1]), fmaxf(s[0][2], s[0][3])),
                     fmaxf(fmaxf(s[1][0], s[1][1]), fmaxf(s[1][2], s[1][3])));
    pm = fmaxf(pm, fmaxf(fmaxf(fmaxf(s[2][0], s[2][1]), fmaxf(s[2][2], s[2][3])),
                         fmaxf(fmaxf(s[3][0], s[3][1]), fmaxf(s[3][2], s[3][3]))));
    pm = fmaxf(pm, __shfl_xor(pm, 16));
    pm = fmaxf(pm, __shfl_xor(pm, 32));
    if (!__all(pm <= m + 11.5f)) {     // T13 defer-max (log2 domain, thr = 8*log2e)
      float mn = fmaxf(m, pm);
      float al = __builtin_exp2f(m - mn);
      m = mn; lsum *= al;
#pragma unroll
      for (int df = 0; df < 4; ++df)
#pragma unroll
        for (int r = 0; r < 4; ++r) ctx[df][r] *= al;
    }
    float lp = 0.f;
#pragma unroll
    for (int mf = 0; mf < 4; ++mf)
#pragma unroll
      for (int r = 0; r < 4; ++r) {
        float p = __builtin_exp2f(s[mf][r] - m);
        s[mf][r] = p;
        lp += p;
      }
    lsum += lp;                        // cross-l4 sum deferred to the end
    // pack P^T to bf16 pairs
    unsigned int pk[4][2];
#pragma unroll
    for (int mf = 0; mf < 4; ++mf) {
      asm("v_cvt_pk_bf16_f32 %0, %1, %2" : "=v"(pk[mf][0]) : "v"(s[mf][0]), "v"(s[mf][1]));
      asm("v_cvt_pk_bf16_f32 %0, %1, %2" : "=v"(pk[mf][1]) : "v"(s[mf][2]), "v"(s[mf][3]));
    }
    // ctx^T += V^T P^T
#pragma unroll
    for (int kk = 0; kk < 2; ++kk) {
      unsigned int q00 = __shfl((int)pk[2 * kk][0], srcA);
      unsigned int q10 = __shfl((int)pk[2 * kk + 1][0], srcA);
      unsigned int q01 = __shfl((int)pk[2 * kk][1], srcA);
      unsigned int q11 = __shfl((int)pk[2 * kk + 1][1], srcA);
      unsigned int r00 = __shfl((int)pk[2 * kk][0], srcB);
      unsigned int r10 = __shfl((int)pk[2 * kk + 1][0], srcB);
      unsigned int r01 = __shfl((int)pk[2 * kk][1], srcB);
      unsigned int r11 = __shfl((int)pk[2 * kk + 1][1], srcB);
      uint4 uu;
      uu.x = hi ? q10 : q00;
      uu.y = hi ? q11 : q01;
      uu.z = hi ? r10 : r00;
      uu.w = hi ? r11 : r01;
      bf16x8 pfrag = *(bf16x8*)&uu;
      int cb = kk * 64 + l4 * 16;
      __builtin_amdgcn_s_setprio(1);
#pragma unroll
      for (int df = 0; df < 4; ++df) {
        int rv = df * 16 + l15;
        bf16x8 vf = *(const bf16x8*)(sV + rv * 128 + (cb ^ ((rv & 7) << 4)));
        ctx[df] = __builtin_amdgcn_mfma_f32_16x16x32_bf16(vf, pfrag, ctx[df], 0, 0, 0);
      }
      __builtin_amdgcn_s_setprio(0);
    }
    __builtin_amdgcn_s_barrier();      // before next iter's stage overwrites buffer d^1
    d ^= 1;
  }
  lsum += __shfl_xor(lsum, 16);
  lsum += __shfl_xor(lsum, 32);
  // write fp32 unnormalized partials (float4: 4 consecutive d) + (m, lsum)
  size_t g = (size_t)bb * 2048 + q0 + l15;
#pragma unroll
  for (int df = 0; df < 4; ++df) {
    f32x4 c = ctx[df];
    *(float4*)(ctxp + ((size_t)half * 16384 + g) * 64 + df * 16 + l4 * 4) =
        *(float4*)&c;
  }
  if (l4 == 0) {
    float2 ml = make_float2(m, lsum);
    *(float2*)(mlp + ((size_t)half * 16384 + g) * 2) = ml;
  }
}

// ---------- 4. proj GEMM fused with KV-half combine ----------
// grid (256 m-blocks, 8 n-blocks). BM=64, BN=256, K=64. 256 thr = 4 waves.
__global__ __launch_bounds__(256) void k_proj(const float* __restrict__ ctxp,
                                              const float* __restrict__ mlp,
                                              const unsigned short* __restrict__ wpT,
                                              const float* __restrict__ b_proj,
                                              float* __restrict__ out) {
  __shared__ __align__(16) char lds[40960];   // sA: 0..8KB ; sB: 8192..40KB
  const int t = threadIdx.x;
  const int lane = t & 63, w = t >> 6;
  const int l15 = lane & 15, l4 = lane >> 4;
  const int m0 = blockIdx.x * 64;
  const int n0 = blockIdx.y * 256;

  // stage sA: combine two halves -> bf16 [64][64], swizzled
  {
    int r_ = t >> 2;
    int dq = (t & 3) << 4;               // 16 d values
    size_t g = (size_t)m0 + r_;
    float m0v = mlp[g * 2], l0v = mlp[g * 2 + 1];
    float m1v = mlp[((size_t)16384 + g) * 2], l1v = mlp[((size_t)16384 + g) * 2 + 1];
    float M = fmaxf(m0v, m1v);
    float a0 = __builtin_exp2f(m0v - M), a1 = __builtin_exp2f(m1v - M);
    float inv = 1.0f / (l0v * a0 + l1v * a1);
    a0 *= inv; a1 *= inv;
    const float4* h0 = (const float4*)(ctxp + g * 64 + dq);
    const float4* h1 = (const float4*)(ctxp + ((size_t)16384 + g) * 64 + dq);
    int sw = (r_ & 7) << 4;
#pragma unroll
    for (int q = 0; q < 2; ++q) {
      float4 v0a = h0[q * 2], v0b = h0[q * 2 + 1];
      float4 v1a = h1[q * 2], v1b = h1[q * 2 + 1];
      u16x8 o;
      o[0] = f2bf(v0a.x * a0 + v1a.x * a1); o[1] = f2bf(v0a.y * a0 + v1a.y * a1);
      o[2] = f2bf(v0a.z * a0 + v1a.z * a1); o[3] = f2bf(v0a.w * a0 + v1a.w * a1);
      o[4] = f2bf(v0b.x * a0 + v1b.x * a1); o[5] = f2bf(v0b.y * a0 + v1b.y * a1);
      o[6] = f2bf(v0b.z * a0 + v1b.z * a1); o[7] = f2bf(v0b.w * a0 + v1b.w * a1);
      *(u16x8*)(lds + r_ * 128 + ((dq * 2 + q * 16) ^ sw)) = o;
    }
  }
  // stage sB: wpT rows n0..n0+255 (full K=64 row = 128B each)
#pragma unroll
  for (int p = 0; p < 8; ++p) {
    int L = p * 4096 + t * 16;
    int row = L >> 7;
    int cb = (L & 127) ^ ((row & 7) << 4);
    GLD16((const char*)wpT + (size_t)(n0 + row) * 128 + cb,
          lds + 8192 + p * 4096 + (w << 10));
  }
  __syncthreads();

  f32x4 acc[4][4] = {};
#pragma unroll
  for (int kk = 0; kk < 2; ++kk) {
    int cb = kk * 64 + l4 * 16;
    bf16x8 af[4], bfr[4];
#pragma unroll
    for (int m = 0; m < 4; ++m) {
      int r = m * 16 + l15;
      af[m] = *(const bf16x8*)(lds + r * 128 + (cb ^ ((r & 7) << 4)));
    }
#pragma unroll
    for (int n = 0; n < 4; ++n) {
      int r = w * 64 + n * 16 + l15;
      bfr[n] = *(const bf16x8*)(lds + 8192 + r * 128 + (cb ^ ((r & 7) << 4)));
    }
    // swapped: D col = ctx-row (out row), D row = wp-row (out col)
#pragma unroll
    for (int m = 0; m < 4; ++m)
#pragma unroll
      for (int n = 0; n < 4; ++n)
        acc[m][n] = __builtin_amdgcn_mfma_f32_16x16x32_bf16(bfr[n], af[m], acc[m][n], 0, 0, 0);
  }
#pragma unroll
  for (int m = 0; m < 4; ++m)
#pragma unroll
    for (int n = 0; n < 4; ++n) {
      int grow = m0 + m * 16 + l15;
      int gcol = n0 + w * 64 + n * 16 + l4 * 4;
      float4 bias = *(const float4*)(b_proj + gcol);
      float4 o;
      o.x = acc[m][n][0] + bias.x; o.y = acc[m][n][1] + bias.y;
      o.z = acc[m][n][2] + bias.z; o.w = acc[m][n][3] + bias.w;
      *(float4*)(out + (size_t)grow * 2048 + gcol) = o;
    }
}

// ---------- launch ----------
extern "C" void kernel_launch(void* const* d_in, const int* in_sizes, int n_in,
                              void* d_out, int out_size, void* d_ws, size_t ws_size,
                              hipStream_t stream) {
  const float* x      = (const float*)d_in[0];
  const float* W_qkv  = (const float*)d_in[1];
  const float* b_qkv  = (const float*)d_in[2];
  const float* W_proj = (const float*)d_in[3];
  const float* b_proj = (const float*)d_in[4];
  float* out = (float*)d_out;

  unsigned short* ws   = (unsigned short*)d_ws;
  unsigned short* wqT  = ws;                                   // 192*2048
  unsigned short* wpT  = wqT + (size_t)192 * 2048;             // 2048*64
  unsigned short* qb   = wpT + (size_t)2048 * 64;              // 16384*64 (pre-scaled)
  unsigned short* kb   = qb  + (size_t)16384 * 64;
  unsigned short* vt   = kb  + (size_t)16384 * 64;             // [8][64][2048]
  float* ctxp = (float*)(vt + (size_t)16384 * 64);             // [2][16384][64] fp32
  float* mlp  = ctxp + (size_t)2 * 16384 * 64;                 // [2][16384][2]

  k_trw<<<64, 256, 0, stream>>>(W_qkv, W_proj, wqT, wpT);
  k_qkv<<<256, 512, 0, stream>>>(x, wqT, b_qkv, qb, kb, vt);
  k_attn<<<dim3(32, 8, 2), 256, 0, stream>>>(qb, kb, vt, ctxp, mlp);
  k_proj<<<dim3(256, 8), 256, 0, stream>>>(ctxp, mlp, wpT, b_proj, out);
}